// Round 16
// baseline (31.233 us; speedup 1.0000x reference)
//
#include <hip/hip_runtime.h>

// B=4, LQ=256, LK=512, DQ=DK=DV=256, H=128
#define B_   4
#define LQ_  256
#define LK_  512
#define DQK_ 256
#define DV_  256
#define H_   128

#define TANH_C 2.8853900817779268f   // 2*log2(e): tanh(x) = 1 - 2/(exp2(TANH_C*x)+1)
#define L2E    1.4426950408889634f
#define NQBLK (B_ * LQ_ / 4)         // 256 q-proj blocks (TILE=4)
#define NKBLK (B_ * LK_ / 4)         // 512 k-proj blocks

// R16: k-split attention. Each (b,qt) tile is computed by TWO blocks, one per
// k-half (halves the per-block ekT/values read volume: 190MB -> 96MB of cold
// L2/fabric traffic, doubles block-level miss concurrency; 48KB LDS -> 2
// blocks/CU). No-max softmax partials combine additively in a tiny 3rd kernel:
// out = (pv0+pv1) / (s0+s1).

// ---------------------------------------------------------------------------
// proj_kernel (R4-exact, proven): fused q+k projection. TILE=4, 128 threads.
// ---------------------------------------------------------------------------
__global__ __launch_bounds__(128) void proj_kernel(const float* __restrict__ Q,
                                                   const float* __restrict__ K,
                                                   const float* __restrict__ Wq,
                                                   const float* __restrict__ Wk,
                                                   float* __restrict__ eq,
                                                   float* __restrict__ ekT) {
    const int blk = blockIdx.x;
    const bool isq = blk < NQBLK;
    const float* in = isq ? Q  : K;
    const float* W  = isq ? Wq : Wk;
    const int r0 = (isq ? blk : blk - NQBLK) * 4;
    const int t  = threadIdx.x;

    float acc0 = 0.f, acc1 = 0.f, acc2 = 0.f, acc3 = 0.f;
    const float4* in4 = reinterpret_cast<const float4*>(in + (size_t)r0 * DQK_);
    for (int d4 = 0; d4 < DQK_ / 4; ++d4) {
        float4 r0v = in4[0 * (DQK_ / 4) + d4];   // uniform -> s_load
        float4 r1v = in4[1 * (DQK_ / 4) + d4];
        float4 r2v = in4[2 * (DQK_ / 4) + d4];
        float4 r3v = in4[3 * (DQK_ / 4) + d4];
#pragma unroll
        for (int e = 0; e < 4; ++e) {
            float w = W[(size_t)(4 * d4 + e) * H_ + t];   // coalesced
            acc0 = fmaf(reinterpret_cast<const float*>(&r0v)[e], w, acc0);
            acc1 = fmaf(reinterpret_cast<const float*>(&r1v)[e], w, acc1);
            acc2 = fmaf(reinterpret_cast<const float*>(&r2v)[e], w, acc2);
            acc3 = fmaf(reinterpret_cast<const float*>(&r3v)[e], w, acc3);
        }
    }
    float e0 = __builtin_amdgcn_exp2f(acc0 * TANH_C);
    float e1 = __builtin_amdgcn_exp2f(acc1 * TANH_C);
    float e2 = __builtin_amdgcn_exp2f(acc2 * TANH_C);
    float e3 = __builtin_amdgcn_exp2f(acc3 * TANH_C);
    if (isq) {
        eq[(size_t)(r0 + 0) * H_ + t] = e0;
        eq[(size_t)(r0 + 1) * H_ + t] = e1;
        eq[(size_t)(r0 + 2) * H_ + t] = e2;
        eq[(size_t)(r0 + 3) * H_ + t] = e3;
    } else {
        const int b  = r0 >> 9;
        const int k0 = r0 & (LK_ - 1);
        float* o = ekT + ((size_t)(b * H_ + t)) * LK_ + k0;
        *reinterpret_cast<float4*>(o) = make_float4(e0, e1, e2, e3);
    }
}

// ---------------------------------------------------------------------------
// attn_half: 512 blocks x 512 threads (8 waves, ~48KB LDS -> 2 blocks/CU).
//   blk = (bq<<1)|half, bq = b*64+qt. Block handles 4 q-rows x 256 k's.
//   Phase B: thread (hs=t>>6, quad=t&63): k-quad x 16-h-slice x 4 rows,
//            acc[16]; partials -> partB[8][64][20].
//   Score:   reduce h-slices, e = (kg<valid) ? exp2(s*L2E) : 0 -> sc[k][r].
//   Partial row sums -> spart[half][row]; partial PV -> pvpart[half][row][v].
// ---------------------------------------------------------------------------
__global__ __launch_bounds__(512) void attn_half(
    const float* __restrict__ eq,          // [B*LQ, H]
    const float* __restrict__ ekT,         // [B, H, LK]
    const float* __restrict__ wv,          // [H]
    const float* __restrict__ values,      // [B, LK, DV]
    const int*   __restrict__ valid_lens,  // [B]
    float* __restrict__ pvpart,            // [2][1024][DV]
    float* __restrict__ spart) {           // [2][1024]
    __shared__ float eq_l[4][H_];          // 2 KB
    __shared__ float wm2[H_];              // 512 B
    __shared__ float sc[256][4];           // 4 KB
    __shared__ float scratch[8 * 64 * 20]; // 40 KB: partB then partD
    __shared__ float red[8];

    float (*partB)[64][20] = reinterpret_cast<float (*)[64][20]>(scratch);
    float (*partD)[4][DV_] = reinterpret_cast<float (*)[4][DV_]>(scratch);

    const int blk  = blockIdx.x;           // (bq<<1)|half
    const int half = blk & 1;
    const int bq   = blk >> 1;             // b*64 + qt
    const int b    = bq >> 6;
    const int qt   = bq & 63;
    const int t    = threadIdx.x;          // 0..511

    eq_l[t >> 7][t & 127] = eq[(size_t)(b * LQ_ + qt * 4 + (t >> 7)) * H_ + (t & 127)];
    if (t < H_) wm2[t] = -2.f * wv[t];
    __syncthreads();

    const int valid  = valid_lens[b];
    const int vlocal = min(256, max(0, valid - half * 256));  // valid k's in this half

    // ---- Phase B: register-blocked partial scores over 256 k's ----
    {
        const int quad = t & 63;           // local k-quad
        const int hs   = t >> 6;           // h-slice 0..7
        const int k0g  = half * 256 + 4 * quad;
        float acc[16];
#pragma unroll
        for (int i = 0; i < 16; ++i) acc[i] = 0.f;

        if (k0g < valid) {
            const float* ekb = ekT + (size_t)b * H_ * LK_ + k0g;
#pragma unroll 2
            for (int hh = 0; hh < 16; ++hh) {
                const int h = 16 * hs + hh;
                float4 ek = *reinterpret_cast<const float4*>(ekb + (size_t)h * LK_);
                float w = wm2[h];          // LDS broadcast
#pragma unroll
                for (int r = 0; r < 4; ++r) {
                    float qv = eq_l[r][h]; // LDS broadcast
                    acc[4 * r + 0] = fmaf(w, __builtin_amdgcn_rcpf(fmaf(qv, ek.x, 1.f)), acc[4 * r + 0]);
                    acc[4 * r + 1] = fmaf(w, __builtin_amdgcn_rcpf(fmaf(qv, ek.y, 1.f)), acc[4 * r + 1]);
                    acc[4 * r + 2] = fmaf(w, __builtin_amdgcn_rcpf(fmaf(qv, ek.z, 1.f)), acc[4 * r + 2]);
                    acc[4 * r + 3] = fmaf(w, __builtin_amdgcn_rcpf(fmaf(qv, ek.w, 1.f)), acc[4 * r + 3]);
                }
            }
        }
        float* pb = &partB[hs][quad][0];
#pragma unroll
        for (int i = 0; i < 4; ++i)
            *reinterpret_cast<float4*>(pb + 4 * i) = *reinterpret_cast<float4*>(&acc[4 * i]);
    }
    __syncthreads();

    // ---- Score stage: reduce 8 h-slices, exp2, mask -> sc[k][r] ----
#pragma unroll
    for (int j = 0; j < 2; ++j) {
        const int o    = t + 512 * j;      // 0..1023
        const int quad = o >> 4;
        const int idx  = o & 15;           // r*4 + e
        const int kl   = 4 * quad + (idx & 3);
        float s = 0.f;
#pragma unroll
        for (int hs = 0; hs < 8; ++hs) s += partB[hs][quad][idx];
        sc[kl][idx >> 2] = (kl < vlocal) ? __builtin_amdgcn_exp2f(s * L2E) : 0.f;
    }
    __syncthreads();

    // ---- Partial row sums (2 waves per row) ----
    {
        const int qi = t >> 7;             // 0..3, wave-uniform (wave>>1)
        const int kl = t & 127;
        float ss = sc[kl][qi] + sc[kl + 128][qi];
#pragma unroll
        for (int off = 32; off; off >>= 1) ss += __shfl_down(ss, off, 64);
        if ((t & 63) == 0) red[t >> 6] = ss;
    }
    __syncthreads();
    if (t < 4) {
        spart[half * 1024 + bq * 4 + t] = red[2 * t] + red[2 * t + 1];
    }
    __syncthreads();                        // fence partB before partD reuse

    // ---- Phase D: partial PV over this k-half ----
    {
        const int w    = __builtin_amdgcn_readfirstlane(t >> 6);  // wave 0..7
        const int v    = 4 * (t & 63);
        const int klo  = 32 * w;
        const int kend = min(klo + 32, vlocal);
        const float* vb = values + ((size_t)b * LK_ + half * 256) * DV_ + v;
        float4 a0 = make_float4(0.f, 0.f, 0.f, 0.f);
        float4 a1 = a0, a2 = a0, a3 = a0;
#pragma unroll 2
        for (int k = klo; k < kend; ++k) {
            float4 sv = *reinterpret_cast<const float4*>(&sc[k][0]);       // broadcast
            float4 vv = *reinterpret_cast<const float4*>(vb + (size_t)k * DV_); // coalesced
            a0.x = fmaf(sv.x, vv.x, a0.x); a0.y = fmaf(sv.x, vv.y, a0.y);
            a0.z = fmaf(sv.x, vv.z, a0.z); a0.w = fmaf(sv.x, vv.w, a0.w);
            a1.x = fmaf(sv.y, vv.x, a1.x); a1.y = fmaf(sv.y, vv.y, a1.y);
            a1.z = fmaf(sv.y, vv.z, a1.z); a1.w = fmaf(sv.y, vv.w, a1.w);
            a2.x = fmaf(sv.z, vv.x, a2.x); a2.y = fmaf(sv.z, vv.y, a2.y);
            a2.z = fmaf(sv.z, vv.z, a2.z); a2.w = fmaf(sv.z, vv.w, a2.w);
            a3.x = fmaf(sv.w, vv.x, a3.x); a3.y = fmaf(sv.w, vv.y, a3.y);
            a3.z = fmaf(sv.w, vv.z, a3.z); a3.w = fmaf(sv.w, vv.w, a3.w);
        }
        *reinterpret_cast<float4*>(&partD[w][0][v]) = a0;
        *reinterpret_cast<float4*>(&partD[w][1][v]) = a1;
        *reinterpret_cast<float4*>(&partD[w][2][v]) = a2;
        *reinterpret_cast<float4*>(&partD[w][3][v]) = a3;
    }
    __syncthreads();
#pragma unroll
    for (int j = 0; j < 2; ++j) {
        const int idx = t + 512 * j;       // 0..1023
        const int r   = idx >> 8;
        const int v   = idx & 255;
        float s = 0.f;
#pragma unroll
        for (int w = 0; w < 8; ++w) s += partD[w][r][v];
        pvpart[((size_t)half * 1024 + bq * 4 + r) * DV_ + v] = s;
    }
}

// ---------------------------------------------------------------------------
// combine: 256 blocks x 1024 threads. out = (pv0+pv1) / (s0+s1).
// ---------------------------------------------------------------------------
__global__ __launch_bounds__(1024) void combine_kernel(
    const float* __restrict__ pvpart,      // [2][1024][DV]
    const float* __restrict__ spart,       // [2][1024]
    float* __restrict__ out) {             // [1024, DV]
    const int bq  = blockIdx.x;            // 0..255
    const int t   = threadIdx.x;
    const int r   = t >> 8;                // 0..3
    const int v   = t & 255;
    const int row = bq * 4 + r;
    const float p = pvpart[(size_t)row * DV_ + v] +
                    pvpart[(size_t)(1024 + row) * DV_ + v];
    const float s = spart[row] + spart[1024 + row];
    out[(size_t)row * DV_ + v] = p * (1.f / s);
}

extern "C" void kernel_launch(void* const* d_in, const int* in_sizes, int n_in,
                              void* d_out, int out_size, void* d_ws, size_t ws_size,
                              hipStream_t stream) {
    const float* queries    = (const float*)d_in[0];  // [B, LQ, DQ]
    const float* keys       = (const float*)d_in[1];  // [B, LK, DK]
    const float* values     = (const float*)d_in[2];  // [B, LK, DV]
    const float* Wq         = (const float*)d_in[3];  // [DQ, H]
    const float* Wk         = (const float*)d_in[4];  // [DK, H]
    const float* wv         = (const float*)d_in[5];  // [H]
    const int*   valid_lens = (const int*)d_in[6];    // [B]
    float* out = (float*)d_out;

    float* eq     = (float*)d_ws;                       // [B*LQ, H]     512 KB
    float* ekT    = eq     + (size_t)B_ * LQ_ * H_;     // [B, H, LK]    1 MB
    float* pvpart = ekT    + (size_t)B_ * H_ * LK_;     // [2][1024][DV] 2 MB
    float* spart  = pvpart + (size_t)2 * 1024 * DV_;    // [2][1024]     8 KB

    proj_kernel   <<<NQBLK + NKBLK, 128, 0, stream>>>(queries, keys, Wq, Wk, eq, ekT);
    attn_half     <<<2 * B_ * LQ_ / 4, 512, 0, stream>>>(eq, ekT, wv, values,
                                                         valid_lens, pvpart, spart);
    combine_kernel<<<B_ * LQ_ / 4, 1024, 0, stream>>>(pvpart, spart, out);
}